// Round 6
// baseline (873.413 us; speedup 1.0000x reference)
//
#include <hip/hip_runtime.h>
#include <hip/hip_bf16.h>

// TemporalSpikeCoder latency encoding:
//   spike_times[b,f] = (int)((1 - x[b,f]) * 100)
//   out[b,t,f] = (spike_times[b,f] == t) ? 1.0f : 0.0f
// x [B=2048, F=1024] f32 (8.4 MB), out [B, T=100, F] f32 (839 MB).
//
// Write-BW-bound. A/B vs R4: identical dense-rolling-window grid-stride
// kernel, but NORMAL stores instead of nontemporal. The harness fill kernel
// (dense window, normal stores) sustains 6.2 TB/s pure-write; R4 (dense
// window, nt stores) ran ~2.7 TB/s. Hypothesis: `nt` bypasses L2 write
// combining and caps the stream; removing it should reach fill-like BW.

constexpr int F  = 1024;
constexpr int T  = 100;
constexpr int F4 = F / 4;      // 256 float4s per feature row

typedef float v4f __attribute__((ext_vector_type(4)));

__global__ __launch_bounds__(256) void TemporalSpikeCoder_78125455114738_kernel(
    const float* __restrict__ x, float* __restrict__ out, int total4) {
    const int gsz = gridDim.x * blockDim.x;
    const v4f* __restrict__ x4 = reinterpret_cast<const v4f*>(x);
    v4f* __restrict__ o4 = reinterpret_cast<v4f*>(out);

    for (int i = blockIdx.x * blockDim.x + threadIdx.x; i < total4; i += gsz) {
        const unsigned f4 = (unsigned)i & (F4 - 1);   // feature float4 index
        const unsigned bt = (unsigned)i >> 8;         // b*T + t
        const unsigned b  = bt / T;                   // magic-mul div
        const int      t  = (int)(bt - b * T);

        const v4f xv = x4[b * F4 + f4];               // L2-hit after first touch
        // Match JAX: f32 math, truncation on int32 cast.
        v4f v;
        v.x = ((int)((1.0f - xv.x) * 100.0f) == t) ? 1.0f : 0.0f;
        v.y = ((int)((1.0f - xv.y) * 100.0f) == t) ? 1.0f : 0.0f;
        v.z = ((int)((1.0f - xv.z) * 100.0f) == t) ? 1.0f : 0.0f;
        v.w = ((int)((1.0f - xv.w) * 100.0f) == t) ? 1.0f : 0.0f;

        o4[i] = v;   // normal store: dense linear stream through L2
    }
}

extern "C" void kernel_launch(void* const* d_in, const int* in_sizes, int n_in,
                              void* d_out, int out_size, void* d_ws, size_t ws_size,
                              hipStream_t stream) {
    const float* x = (const float*)d_in[0];
    float* out = (float*)d_out;
    const int total4 = out_size / 4;                  // 52,428,800 float4 stores
    const int block = 256;
    const int grid = 2048;                            // 8 blocks/CU, grid-stride
    TemporalSpikeCoder_78125455114738_kernel<<<grid, block, 0, stream>>>(x, out, total4);
}

// Round 9
// 814.207 us; speedup vs baseline: 1.0727x; 1.0727x over previous
//
#include <hip/hip_runtime.h>
#include <hip/hip_bf16.h>

// TemporalSpikeCoder latency encoding:
//   out[b,t,f] = ((int)((1 - x[b,f]) * 100) == t) ? 1.0f : 0.0f
// x [2048,1024] f32 (8.4 MB), out [2048,100,1024] f32 (839 MB). Write-bound.
//
// R2/R4/R6 all landed at ~2.6-3.1 TB/s effective write BW regardless of
// write pattern (block-local vs dense-linear) and store type (nt vs normal).
// The harness fill kernel sustains 6.2 TB/s at ~10% occupancy (~4 waves/CU).
// Hypothesis: thousands of concurrent write streams (32 waves/CU) fragment
// DRAM sequential runs; a few long streams per CU (fill's config) don't.
// This version mimics fill: grid=256 (1 block/CU, 4 waves/CU), x loaded
// once into registers, then a pure unrolled store loop (8 independent
// stores back-to-back per t step).

constexpr int F   = 1024;
constexpr int T   = 100;
constexpr int F4  = F / 4;   // 256 float4s per row
constexpr int RPB = 8;       // batch rows per block

typedef float v4f __attribute__((ext_vector_type(4)));

__global__ __launch_bounds__(256) void TemporalSpikeCoder_78125455114738_kernel(
    const float* __restrict__ x, float* __restrict__ out) {
    const int b0 = blockIdx.x * RPB;       // first batch row of this block
    const int f4 = threadIdx.x;            // float4 index within row

    const v4f* __restrict__ x4 = reinterpret_cast<const v4f*>(x);
    v4f* __restrict__ o4 = reinterpret_cast<v4f*>(out);

    // Load this thread's 8 x-float4s once (32 VGPR), convert to spike times.
    int sx[RPB], sy[RPB], sz[RPB], sw[RPB];
    #pragma unroll
    for (int r = 0; r < RPB; ++r) {
        const v4f xv = x4[(b0 + r) * F4 + f4];
        // Match JAX: f32 math, truncation toward zero on int32 cast.
        sx[r] = (int)((1.0f - xv.x) * 100.0f);
        sy[r] = (int)((1.0f - xv.y) * 100.0f);
        sz[r] = (int)((1.0f - xv.z) * 100.0f);
        sw[r] = (int)((1.0f - xv.w) * 100.0f);
    }

    // Pure write loop: per t, 8 independent coalesced stores (one per row).
    v4f* o = o4 + (size_t)b0 * (T * F4) + f4;
    for (int t = 0; t < T; ++t) {
        #pragma unroll
        for (int r = 0; r < RPB; ++r) {
            v4f v;
            v.x = (sx[r] == t) ? 1.0f : 0.0f;
            v.y = (sy[r] == t) ? 1.0f : 0.0f;
            v.z = (sz[r] == t) ? 1.0f : 0.0f;
            v.w = (sw[r] == t) ? 1.0f : 0.0f;
            o[(size_t)r * (T * F4) + (size_t)t * F4] = v;
        }
    }
}

extern "C" void kernel_launch(void* const* d_in, const int* in_sizes, int n_in,
                              void* d_out, int out_size, void* d_ws, size_t ws_size,
                              hipStream_t stream) {
    const float* x = (const float*)d_in[0];
    float* out = (float*)d_out;
    const int B = in_sizes[0] / F;              // 2048
    const int grid = B / RPB;                   // 256 blocks = 1 per CU
    TemporalSpikeCoder_78125455114738_kernel<<<grid, 256, 0, stream>>>(x, out);
}